// Round 10
// baseline (520.730 us; speedup 1.0000x reference)
//
#include <hip/hip_runtime.h>
#include <math.h>

#define TSEQ 512
#define FDIM 64
#define HDIM 128
#define NB   512

typedef _Float16 f16x8 __attribute__((ext_vector_type(8)));
typedef __fp16  fp16x2 __attribute__((ext_vector_type(2)));
typedef __attribute__((ext_vector_type(4))) float f32x4;

#define H_ROW 136                 // halves per batch row (+8 pad)
#define H_BUF (16 * H_ROW)

__device__ __forceinline__ float fast_sig(float x) {
    return __builtin_amdgcn_rcpf(1.0f + __expf(-x));
}
__device__ __forceinline__ float fast_tanh(float x) {
    return 1.0f - 2.0f * __builtin_amdgcn_rcpf(1.0f + __expf(2.0f * x));
}
__device__ __forceinline__ f32x4 mfma16f(f16x8 a, f16x8 b, f32x4 c) {
    return __builtin_amdgcn_mfma_f32_16x16x32_f16(a, b, c, 0, 0, 0);
}

union PU { fp16x2 h2[4]; f16x8 v; };
union GU { uint2 u; _Float16 h[4]; };

// 16 f32 (two float4) -> one f16x8 fragment (RTZ pack, x path)
__device__ __forceinline__ f16x8 pack_f16(float4 a, float4 b) {
    PU u;
    u.h2[0] = __builtin_amdgcn_cvt_pkrtz(a.x, a.y);
    u.h2[1] = __builtin_amdgcn_cvt_pkrtz(a.z, a.w);
    u.h2[2] = __builtin_amdgcn_cvt_pkrtz(b.x, b.y);
    u.h2[3] = __builtin_amdgcn_cvt_pkrtz(b.z, b.w);
    return u.v;
}

// Raw barrier: drain LDS only; global loads/stores stay in flight.
__device__ __forceinline__ void wg_barrier() {
    __builtin_amdgcn_sched_barrier(0);
    asm volatile("s_waitcnt lgkmcnt(0)" ::: "memory");
    __builtin_amdgcn_s_barrier();
    asm volatile("" ::: "memory");
    __builtin_amdgcn_sched_barrier(0);
}

// ---------------- pre-GEMM: gi[t][b][384] (fp16) = x(t,b,:)·W_ih^T + biases
// 1024 blocks x 512 thr on all CUs; no LDS, no barriers. Wave w owns gate
// rows [16w,16w+16) of each kind; biases folded (r,z: bi+bh; n: bi only).
__global__ __launch_bounds__(512)
void gi_gemm16(const float* __restrict__ x,
               const float* __restrict__ W_ih,
               const float* __restrict__ b_ih,
               const float* __restrict__ b_hh,
               _Float16* __restrict__ gi)
{
    const int tid  = threadIdx.x;
    const int w    = tid >> 6;
    const int lane = tid & 63;
    const int g4   = lane >> 4;
    const int bcol = lane & 15;
    const int b0   = blockIdx.x * 16;
    const int t0   = blockIdx.y * 16;

    f16x8 WihF[3][2];
    #pragma unroll
    for (int kd = 0; kd < 3; ++kd) {
        const int g = kd * 128 + w * 16 + bcol;
        #pragma unroll
        for (int kt = 0; kt < 2; ++kt) {
            const float* pw = W_ih + g * FDIM + kt * 32 + g4 * 8;
            f16x8 v;
            #pragma unroll
            for (int e = 0; e < 8; ++e) v[e] = (_Float16)pw[e];
            WihF[kd][kt] = v;
        }
    }
    f32x4 biasR, biasZ, biasN;
    #pragma unroll
    for (int i = 0; i < 4; ++i) {
        const int gr = w * 16 + g4 * 4 + i;
        biasR[i] = b_ih[gr]       + b_hh[gr];
        biasZ[i] = b_ih[128 + gr] + b_hh[128 + gr];
        biasN[i] = b_ih[256 + gr];
    }

    for (int tt = 0; tt < 16; ++tt) {
        const int t = t0 + tt;
        const float* xp = x + ((size_t)(b0 + bcol) * TSEQ + t) * FDIM;
        float4 a0 = *(const float4*)(xp + g4 * 8);
        float4 a1 = *(const float4*)(xp + g4 * 8 + 4);
        float4 a2 = *(const float4*)(xp + 32 + g4 * 8);
        float4 a3 = *(const float4*)(xp + 32 + g4 * 8 + 4);
        f16x8 xf0 = pack_f16(a0, a1);
        f16x8 xf1 = pack_f16(a2, a3);

        f32x4 c0 = biasR, c1 = biasZ, c2 = biasN;
        c0 = mfma16f(WihF[0][0], xf0, c0);
        c0 = mfma16f(WihF[0][1], xf1, c0);
        c1 = mfma16f(WihF[1][0], xf0, c1);
        c1 = mfma16f(WihF[1][1], xf1, c1);
        c2 = mfma16f(WihF[2][0], xf0, c2);
        c2 = mfma16f(WihF[2][1], xf1, c2);

        GU g0, g1, g2;
        #pragma unroll
        for (int i = 0; i < 4; ++i) {
            g0.h[i] = (_Float16)c0[i];   // RNE
            g1.h[i] = (_Float16)c1[i];
            g2.h[i] = (_Float16)c2[i];
        }
        _Float16* gp = gi + ((size_t)t * NB + (b0 + bcol)) * 384 + w * 16 + g4 * 4;
        *(uint2*)(gp)       = g0.u;
        *(uint2*)(gp + 128) = g1.u;
        *(uint2*)(gp + 256) = g2.u;
    }
}

// ---------------- recurrence --------------------------------------------
// 32 blocks x 16 batches, 512 threads = 8 waves (2/SIMD). fp16 single-term
// numerics, f32 accumulate. USE_GI: x-projection precomputed into gi (fp16,
// biases folded) -> per step only 3x8B global loads (2-slot prefetch, 2
// steps ahead) + 12 h-MFMA. !USE_GI: R9's in-loop x path (proven fallback).
// Triple-buffered h/psum + one lgkm-only barrier per step.
template<bool USE_GI>
__global__ __launch_bounds__(512, 2)
void gru_f16(const float* __restrict__ x,
             const float* __restrict__ W_ih,
             const float* __restrict__ W_hh,
             const float* __restrict__ b_ih,
             const float* __restrict__ b_hh,
             const float* __restrict__ W_out,
             const float* __restrict__ b_out,
             const _Float16* __restrict__ gi,
             float* __restrict__ out)
{
    const int tid  = threadIdx.x;
    const int wid  = tid >> 6;        // 0..7
    const int lane = tid & 63;
    const int g4   = lane >> 4;
    const int bcol = lane & 15;
    const int b0   = blockIdx.x * 16;

    __shared__ __align__(16) _Float16 h_s[3][16][H_ROW];
    __shared__ __align__(16) float ps_s[3][16][12];

    // ---- stationary fp16 weights ----
    f16x8 WhhF[3][4];
    f16x8 WihF[3][2];
    #pragma unroll
    for (int kd = 0; kd < 3; ++kd) {
        const int g = kd * 128 + wid * 16 + bcol;
        #pragma unroll
        for (int kt = 0; kt < 4; ++kt) {
            const float* pw = W_hh + g * HDIM + kt * 32 + g4 * 8;
            f16x8 v;
            #pragma unroll
            for (int e = 0; e < 8; ++e) v[e] = (_Float16)pw[e];
            WhhF[kd][kt] = v;
        }
        if constexpr (!USE_GI) {
            #pragma unroll
            for (int kt = 0; kt < 2; ++kt) {
                const float* pw = W_ih + g * FDIM + kt * 32 + g4 * 8;
                f16x8 v;
                #pragma unroll
                for (int e = 0; e < 8; ++e) v[e] = (_Float16)pw[e];
                WihF[kd][kt] = v;
            }
        }
    }

    f32x4 biasR, biasZ, biasNI, biasNH;
    float wout_r[4], h_old[4];
    #pragma unroll
    for (int i = 0; i < 4; ++i) {
        const int gr = wid * 16 + g4 * 4 + i;
        if constexpr (!USE_GI) {
            biasR[i]  = b_ih[gr]       + b_hh[gr];
            biasZ[i]  = b_ih[128 + gr] + b_hh[128 + gr];
            biasNI[i] = b_ih[256 + gr];
        }
        biasNH[i] = b_hh[256 + gr];
        wout_r[i] = W_out[gr];
        h_old[i]  = 0.0f;
    }
    const float bout = b_out[0];

    {   // zero h buffer 0
        unsigned* hp = (unsigned*)&h_s[0][0][0];
        for (int i = tid; i < H_BUF / 2; i += 512) hp[i] = 0u;
    }

    // ---- input pipelines ----
    const float* xb = x + (size_t)(b0 + bcol) * TSEQ * FDIM;
    float4 sA0, sA1, sA2, sA3, sB0, sB1, sB2, sB3;
    f16x8 xf0, xf1;
    GU rA, zA, nA, rB, zB, nB;
    const _Float16* gnext = nullptr;

    if constexpr (USE_GI) {
        const _Float16* gb = gi + (size_t)(b0 + bcol) * 384 + wid * 16 + g4 * 4;
        rA.u = *(const uint2*)(gb);
        zA.u = *(const uint2*)(gb + 128);
        nA.u = *(const uint2*)(gb + 256);
        const _Float16* g1 = gb + (size_t)384 * NB;
        rB.u = *(const uint2*)(g1);
        zB.u = *(const uint2*)(g1 + 128);
        nB.u = *(const uint2*)(g1 + 256);
        gnext = gb + (size_t)2 * 384 * NB;   // target: t = 2
    } else {
        sA0 = *(const float4*)(xb + g4 * 8);
        sA1 = *(const float4*)(xb + g4 * 8 + 4);
        sA2 = *(const float4*)(xb + 32 + g4 * 8);
        sA3 = *(const float4*)(xb + 32 + g4 * 8 + 4);
        const float* xp1 = xb + FDIM;
        sB0 = *(const float4*)(xp1 + g4 * 8);
        sB1 = *(const float4*)(xp1 + g4 * 8 + 4);
        sB2 = *(const float4*)(xp1 + 32 + g4 * 8);
        sB3 = *(const float4*)(xp1 + 32 + g4 * 8 + 4);
        xf0 = pack_f16(sA0, sA1);
        xf1 = pack_f16(sA2, sA3);
    }

    __syncthreads();   // prologue barrier

    const bool outw = (wid == 0) && (lane < 16);
    float* outp = out + (size_t)(b0 + lane) * TSEQ;
    float o0 = 0.f, o1 = 0.f, o2 = 0.f, o3 = 0.f;
    int rb = 0, wb = 1;

// consume gi(s) from slot, reload slot with gi(s+2), advance clamped
#define GI_CONSUME(RS, ZS, NS)                                              \
    a0a = (f32x4){(float)RS.h[0], (float)RS.h[1],                           \
                  (float)RS.h[2], (float)RS.h[3]};                          \
    a1  = (f32x4){(float)ZS.h[0], (float)ZS.h[1],                           \
                  (float)ZS.h[2], (float)ZS.h[3]};                          \
    a2  = (f32x4){(float)NS.h[0], (float)NS.h[1],                           \
                  (float)NS.h[2], (float)NS.h[3]};                          \
    RS.u = *(const uint2*)(gnext);                                          \
    ZS.u = *(const uint2*)(gnext + 128);                                    \
    NS.u = *(const uint2*)(gnext + 256);                                    \
    gnext += (s < TSEQ - 3) ? (size_t)384 * NB : 0;

    for (int t = 0; t < TSEQ; t += 4) {
        #pragma unroll
        for (int u = 0; u < 4; ++u) {
            const int s = t + u;

            // ---- out path: out[s-1] from psum(s-1) (buffer rb) ----
            if (outw && s > 0) {
                f32x4 q0 = *(const f32x4*)&ps_s[rb][lane][0];
                f32x4 q1 = *(const f32x4*)&ps_s[rb][lane][4];
                float sm = (q0[0] + q0[1]) + (q0[2] + q0[3])
                         + (q1[0] + q1[1]) + (q1[2] + q1[3]);
                float val = fast_tanh(sm + bout);
                if (u == 0) {
                    o3 = val;
                    *(float4*)(outp + (t - 4)) = make_float4(o0, o1, o2, o3);
                } else if (u == 1) o0 = val;
                else if (u == 2) o1 = val;
                else o2 = val;
            }

            f32x4 a0, a1, a2, a3;

            if constexpr (USE_GI) {
                // h fragments (issue LDS reads early)
                f16x8 bh0 = *(const f16x8*)&h_s[rb][bcol][0 * 32 + g4 * 8];
                f16x8 bh1 = *(const f16x8*)&h_s[rb][bcol][1 * 32 + g4 * 8];
                f16x8 bh2 = *(const f16x8*)&h_s[rb][bcol][2 * 32 + g4 * 8];
                f16x8 bh3 = *(const f16x8*)&h_s[rb][bcol][3 * 32 + g4 * 8];

                f32x4 a0a;
                if ((u & 1) == 0) { GI_CONSUME(rA, zA, nA) }
                else              { GI_CONSUME(rB, zB, nB) }

                f32x4 a0b = {0.f, 0.f, 0.f, 0.f};
                f32x4 a3a = biasNH, a3b = {0.f, 0.f, 0.f, 0.f};
                // 12 MFMA; a0/a3 as 2-deep split chains, a1 4-deep
                a0a = mfma16f(WhhF[0][0], bh0, a0a);
                a3a = mfma16f(WhhF[2][0], bh0, a3a);
                a1  = mfma16f(WhhF[1][0], bh0, a1);
                a0b = mfma16f(WhhF[0][2], bh2, a0b);
                a3b = mfma16f(WhhF[2][2], bh2, a3b);
                a1  = mfma16f(WhhF[1][1], bh1, a1);
                a0a = mfma16f(WhhF[0][1], bh1, a0a);
                a3a = mfma16f(WhhF[2][1], bh1, a3a);
                a1  = mfma16f(WhhF[1][2], bh2, a1);
                a0b = mfma16f(WhhF[0][3], bh3, a0b);
                a3b = mfma16f(WhhF[2][3], bh3, a3b);
                a1  = mfma16f(WhhF[1][3], bh3, a1);

                a0 = a0a + a0b;
                a3 = a3a + a3b;
            } else {
                // ---- R9 in-loop x path (proven fallback) ----
                {
                    const int tl = (s + 2 < TSEQ) ? (s + 2) : (TSEQ - 1);
                    const float* xp = xb + (size_t)tl * FDIM;
                    if ((u & 1) == 0) {
                        sA0 = *(const float4*)(xp + g4 * 8);
                        sA1 = *(const float4*)(xp + g4 * 8 + 4);
                        sA2 = *(const float4*)(xp + 32 + g4 * 8);
                        sA3 = *(const float4*)(xp + 32 + g4 * 8 + 4);
                    } else {
                        sB0 = *(const float4*)(xp + g4 * 8);
                        sB1 = *(const float4*)(xp + g4 * 8 + 4);
                        sB2 = *(const float4*)(xp + 32 + g4 * 8);
                        sB3 = *(const float4*)(xp + 32 + g4 * 8 + 4);
                    }
                }
                f16x8 bh0 = *(const f16x8*)&h_s[rb][bcol][0 * 32 + g4 * 8];
                f16x8 bh1 = *(const f16x8*)&h_s[rb][bcol][1 * 32 + g4 * 8];
                f16x8 bh2 = *(const f16x8*)&h_s[rb][bcol][2 * 32 + g4 * 8];
                f16x8 bh3 = *(const f16x8*)&h_s[rb][bcol][3 * 32 + g4 * 8];

                f32x4 a0x = biasR, a1x = biasZ, a3l = biasNH;
                a2 = biasNI;
                f32x4 a0h = {0.f,0.f,0.f,0.f}, a1h = {0.f,0.f,0.f,0.f};

                a0x = mfma16f(WihF[0][0], xf0, a0x);
                a0x = mfma16f(WihF[0][1], xf1, a0x);
                a1x = mfma16f(WihF[1][0], xf0, a1x);
                a1x = mfma16f(WihF[1][1], xf1, a1x);
                a2  = mfma16f(WihF[2][0], xf0, a2);
                a2  = mfma16f(WihF[2][1], xf1, a2);

                a0h = mfma16f(WhhF[0][0], bh0, a0h);
                a1h = mfma16f(WhhF[1][0], bh0, a1h);
                a3l = mfma16f(WhhF[2][0], bh0, a3l);
                a0h = mfma16f(WhhF[0][1], bh1, a0h);
                a1h = mfma16f(WhhF[1][1], bh1, a1h);
                a3l = mfma16f(WhhF[2][1], bh1, a3l);
                a0h = mfma16f(WhhF[0][2], bh2, a0h);
                a1h = mfma16f(WhhF[1][2], bh2, a1h);
                a3l = mfma16f(WhhF[2][2], bh2, a3l);
                a0h = mfma16f(WhhF[0][3], bh3, a0h);
                a1h = mfma16f(WhhF[1][3], bh3, a1h);
                a3l = mfma16f(WhhF[2][3], bh3, a3l);

                a0 = a0x + a0h;
                a1 = a1x + a1h;
                a3 = a3l;
            }

            // ---- gates (in-register) ----
            float psum = 0.0f;
            _Float16 h16[4];
            #pragma unroll
            for (int i = 0; i < 4; ++i) {
                float r  = fast_sig(a0[i]);
                float z  = fast_sig(a1[i]);
                float n  = fast_tanh(a2[i] + r * a3[i]);
                float hn = n + z * (h_old[i] - n);
                h_old[i] = hn;
                h16[i]   = (_Float16)hn;   // RNE
                psum = fmaf(wout_r[i], hn, psum);
            }
            psum += __shfl_xor(psum, 16);
            psum += __shfl_xor(psum, 32);

            // ---- writes to wb ----
            {
                union { _Float16 h[4]; uint2 u; } hu;
                hu.h[0] = h16[0]; hu.h[1] = h16[1];
                hu.h[2] = h16[2]; hu.h[3] = h16[3];
                *(uint2*)&h_s[wb][bcol][wid * 16 + g4 * 4] = hu.u;
            }
            if (lane < 16) ps_s[wb][lane][wid] = psum;

            if constexpr (!USE_GI) {
                // convert x(s+1) fragments from the other slot
                if ((u & 1) == 0) {
                    xf0 = pack_f16(sB0, sB1);
                    xf1 = pack_f16(sB2, sB3);
                } else {
                    xf0 = pack_f16(sA0, sA1);
                    xf1 = pack_f16(sA2, sA3);
                }
            }

            wg_barrier();
            rb = wb; wb = (wb == 2) ? 0 : wb + 1;
        }
    }
#undef GI_CONSUME

    // tail: out[511] from psum(511), in buffer (512 % 3) == 2
    if (outw) {
        f32x4 q0 = *(const f32x4*)&ps_s[2][lane][0];
        f32x4 q1 = *(const f32x4*)&ps_s[2][lane][4];
        float sm = (q0[0] + q0[1]) + (q0[2] + q0[3])
                 + (q1[0] + q1[1]) + (q1[2] + q1[3]);
        o3 = fast_tanh(sm + bout);
        *(float4*)(outp + (TSEQ - 4)) = make_float4(o0, o1, o2, o3);
    }
}

extern "C" void kernel_launch(void* const* d_in, const int* in_sizes, int n_in,
                              void* d_out, int out_size, void* d_ws, size_t ws_size,
                              hipStream_t stream) {
    const float* x     = (const float*)d_in[0];
    const float* W_ih  = (const float*)d_in[1];
    const float* W_hh  = (const float*)d_in[2];
    const float* b_ih  = (const float*)d_in[3];
    const float* b_hh  = (const float*)d_in[4];
    const float* W_out = (const float*)d_in[5];
    const float* b_out = (const float*)d_in[6];
    float* out = (float*)d_out;

    const size_t gi_bytes = (size_t)TSEQ * NB * 384 * sizeof(_Float16); // 201 MB
    if (ws_size >= gi_bytes) {
        _Float16* gi = (_Float16*)d_ws;
        gi_gemm16<<<dim3(32, 32), 512, 0, stream>>>(x, W_ih, b_ih, b_hh, gi);
        gru_f16<true><<<32, 512, 0, stream>>>(x, W_ih, W_hh, b_ih, b_hh,
                                              W_out, b_out, gi, out);
    } else {
        gru_f16<false><<<32, 512, 0, stream>>>(x, W_ih, W_hh, b_ih, b_hh,
                                               W_out, b_out, nullptr, out);
    }
}